// Round 6
// baseline (1655.174 us; speedup 1.0000x reference)
//
#include <hip/hip_runtime.h>
#include <hip/hip_bf16.h>

typedef __attribute__((ext_vector_type(8))) short short8;

// ---------------- dtype-agnostic input loading ----------------
// flag==1: inputs are fp32 (proven by R2->R3 parity experiment); flag==0: bf16.
__device__ __forceinline__ float ld_f(const void* p, int f32, int i) {
  if (f32) return ((const float*)p)[i];
  unsigned short u = ((const unsigned short*)p)[i];
  return __uint_as_float(((unsigned)u) << 16);
}
__device__ __forceinline__ float bf_to_f(short s) {
  return __uint_as_float(((unsigned)(unsigned short)s) << 16);
}
__device__ __forceinline__ short f_to_bf(float v) {
  __hip_bfloat16 h = __float2bfloat16(v);
  return *reinterpret_cast<short*>(&h);
}

__global__ void detect_dtype(const unsigned short* __restrict__ xs, int* __restrict__ flag) {
  int t = threadIdx.x;
  int bad = 0;
  for (int j = 2 * t; j < 16384; j += 512) {  // EVEN u16 slots = fp32 low-mantissa garbage
    unsigned e = (xs[j] >> 7) & 0xFF;
    if (e >= 0xF0) bad = 1;
  }
  if (bad) atomicOr(flag, 1);
}

__global__ void conv_bias(const void* bg, const void* bq, const void* bk,
                          const void* bv, const void* bs, const int* __restrict__ flag,
                          float* __restrict__ bgf, float* __restrict__ bias512) {
  int tid = blockIdx.x * blockDim.x + threadIdx.x;
  int f = *flag;
  if (tid < 128) bgf[tid] = ld_f(bg, f, tid);
  else if (tid < 640) {
    int t = tid - 128;
    const void* b = (t < 128) ? bq : (t < 256) ? bk : (t < 384) ? bv : bs;
    bias512[t] = ld_f(b, f, t & 127);
  }
}

// ---------------- naive GEMM h0 = x @ W_gcn (fp32, no MFMA) ----------------
__global__ void naive_h0(const void* __restrict__ x, const void* __restrict__ Wg,
                         const int* __restrict__ flag, float* __restrict__ h0, int M) {
  int tid = blockIdx.x * blockDim.x + threadIdx.x;
  if (tid >= M * 128) return;
  int f = *flag;
  int c = tid & 127, row = tid >> 7;
  float acc = 0.f;
#pragma unroll 8
  for (int k = 0; k < 128; ++k)
    acc += ld_f(x, f, row * 128 + k) * ld_f(Wg, f, k * 128 + c);
  h0[tid] = acc;
}

// ---- naive GEMM [q|k|v|s] = h @ W + bias, routed epilogue (fp32, no MFMA) --
__global__ void naive_qkvs(const float* __restrict__ h, const void* Wq, const void* Wk,
                           const void* Wv, const void* Ws, const int* __restrict__ flag,
                           const float* __restrict__ bias512, short* __restrict__ qb,
                           short* __restrict__ kb, short* __restrict__ vb,
                           float* __restrict__ outacc, int M) {
  int tid = blockIdx.x * blockDim.x + threadIdx.x;
  if (tid >= M * 512) return;
  int f = *flag;
  int col = tid & 511, row = tid >> 9;
  const void* W = (col < 128) ? Wq : (col < 256) ? Wk : (col < 384) ? Wv : Ws;
  int cc = col & 127;
  float acc = bias512[col];
#pragma unroll 8
  for (int k = 0; k < 128; ++k)
    acc += h[row * 128 + k] * ld_f(W, f, k * 128 + cc);
  if (col < 128)      qb[(size_t)row * 128 + cc] = f_to_bf(acc);
  else if (col < 256) kb[(size_t)row * 128 + cc] = f_to_bf(acc);
  else if (col < 384) vb[(size_t)row * 128 + cc] = f_to_bf(acc);
  else                outacc[(size_t)row * 128 + cc] = acc;  // skip: h@Ws+bs
}

// ---------------- GCN ----------------
__global__ void deg_kernel(const int* __restrict__ ei, float* __restrict__ deg, int E) {
  int e = blockIdx.x * blockDim.x + threadIdx.x;
  if (e >= E) return;
  atomicAdd(&deg[ei[E + e]], 1.0f);
}

__global__ void dinv_kernel(float* __restrict__ deg, int N) {
  int i = blockIdx.x * blockDim.x + threadIdx.x;
  if (i >= N) return;
  deg[i] = rsqrtf(deg[i] + 1.0f);  // +1 self-loop; always > 0
}

__global__ void gcn_scatter(const int* __restrict__ ei, const float* __restrict__ dinv,
                            const float* __restrict__ h0, float* __restrict__ hacc, int E) {
  long long tid = (long long)blockIdx.x * blockDim.x + threadIdx.x;
  int e = (int)(tid >> 7), c = (int)(tid & 127);
  if (e >= E) return;
  int s = ei[e], t = ei[E + e];
  float coef = dinv[s] * dinv[t];
  atomicAdd(hacc + (size_t)t * 128 + c, h0[(size_t)s * 128 + c] * coef);
}

// In-place: h0[i] <- relu(hacc[i] + h0[i]*dinv^2 + bg[c])
__global__ void gcn_finish(const float* __restrict__ hacc, float* h0,
                           const float* __restrict__ dinv, const float* __restrict__ bgf,
                           long long total) {
  long long i = (long long)blockIdx.x * blockDim.x + threadIdx.x;
  if (i >= total) return;
  int n = (int)(i >> 7), c = (int)(i & 127);
  float di = dinv[n];
  float v = hacc[i] + h0[i] * di * di + bgf[c];
  h0[i] = v > 0.f ? v : 0.f;
}

// ---------------- attention ----------------
__global__ void fill_mmax(unsigned* __restrict__ mmax, int total) {
  int i = blockIdx.x * blockDim.x + threadIdx.x;
  if (i < total) mmax[i] = 0x007FFFFFu;  // ordered-uint encoding of -inf
}

__global__ void attn_alpha(const int* __restrict__ ei, const short* __restrict__ qb,
                           const short* __restrict__ kb, float* __restrict__ alpha,
                           unsigned* __restrict__ mmax, int E) {
  int tid = blockIdx.x * blockDim.x + threadIdx.x;
  if (tid >= E * 4) return;
  int e = tid >> 2, h = tid & 3;
  int s = ei[e], t = ei[E + e];
  const short8* qp = (const short8*)(qb + (size_t)t * 128 + h * 32);
  const short8* kp = (const short8*)(kb + (size_t)s * 128 + h * 32);
  float dot = 0.f;
#pragma unroll
  for (int b = 0; b < 4; ++b) {
    short8 qa = qp[b], ka = kp[b];
#pragma unroll
    for (int j = 0; j < 8; ++j) dot += bf_to_f(qa[j]) * bf_to_f(ka[j]);
  }
  dot *= 0.17677669529663687f;  // 1/sqrt(32)
  alpha[tid] = dot;
  unsigned bits = __float_as_uint(dot);
  unsigned mapped = (bits & 0x80000000u) ? ~bits : (bits | 0x80000000u);
  atomicMax(&mmax[(size_t)t * 4 + h], mapped);
}

__global__ void attn_denom(const int* __restrict__ ei, const unsigned* __restrict__ mmax,
                           float* __restrict__ alpha, float* __restrict__ denom, int E) {
  int tid = blockIdx.x * blockDim.x + threadIdx.x;
  if (tid >= E * 4) return;
  int e = tid >> 2, h = tid & 3;
  int t = ei[E + e];
  unsigned mm = mmax[(size_t)t * 4 + h];
  float mv = (mm & 0x80000000u) ? __uint_as_float(mm ^ 0x80000000u) : __uint_as_float(~mm);
  float ea = __expf(alpha[tid] - mv);
  alpha[tid] = ea;
  atomicAdd(&denom[(size_t)t * 4 + h], ea);
}

__global__ void rdenom_kernel(float* __restrict__ denom, int total) {
  int i = blockIdx.x * blockDim.x + threadIdx.x;
  if (i >= total) return;
  float d = denom[i];
  denom[i] = d > 0.f ? 1.f / d : 0.f;
}

__global__ void attn_scatter(const int* __restrict__ ei, const float* __restrict__ ea,
                             const float* __restrict__ rdenom, const short* __restrict__ vb,
                             float* __restrict__ outacc, int E) {
  long long tid = (long long)blockIdx.x * blockDim.x + threadIdx.x;
  int e = (int)(tid >> 7), c = (int)(tid & 127);
  if (e >= E) return;
  int s = ei[e], t = ei[E + e];
  int h = c >> 5;
  float w = ea[(size_t)e * 4 + h] * rdenom[(size_t)t * 4 + h];
  float val = w * bf_to_f(vb[(size_t)s * 128 + c]);
  atomicAdd(outacc + (size_t)t * 128 + c, val);
}

// THE ROUND-6 CHANGE: output written as FP32 (reference output dtype is
// float32; the doc rule says d_out is float* then). Everything else == R5.
__global__ void copy_out(const float* __restrict__ acc, float* __restrict__ out,
                         long long total) {
  long long i = (long long)blockIdx.x * blockDim.x + threadIdx.x;
  if (i < total) out[i] = acc[i];
}

// ---------------- launch ----------------
extern "C" void kernel_launch(void* const* d_in, const int* in_sizes, int n_in,
                              void* d_out, int out_size, void* d_ws, size_t ws_size,
                              hipStream_t stream) {
  const void* x  = d_in[0];
  const int* ei  = (const int*)d_in[1];
  const void* Wg = d_in[2];
  const void* bg = d_in[3];
  const void* Wq = d_in[4];
  const void* bq = d_in[5];
  const void* Wk = d_in[6];
  const void* bk = d_in[7];
  const void* Wv = d_in[8];
  const void* bv = d_in[9];
  const void* Ws = d_in[10];
  const void* bs = d_in[11];
  float* out = (float*)d_out;

  const int N = in_sizes[0] / 128;
  const int E = in_sizes[1] / 2;
  long long NC = (long long)N * 128;

  // ---- workspace carve (256B aligned) — total ~101 MB, NO aliasing ----
  char* ws = (char*)d_ws;
  size_t off = 0;
  auto carve = [&](size_t bytes) -> void* {
    void* p = ws + off;
    off += (bytes + 255) & ~(size_t)255;
    return p;
  };
  int* flag = (int*)carve(256);
  float* bias512 = (float*)carve(512 * 4);
  float* bgf = (float*)carve(128 * 4);
  float* deg = (float*)carve((size_t)N * 4);
  float* h0 = (float*)carve((size_t)N * 128 * 4);    // -> h (in-place relu)
  float* hacc = (float*)carve((size_t)N * 128 * 4);  // -> outacc (fully overwritten)
  short* qb = (short*)carve((size_t)N * 128 * 2);
  short* kb = (short*)carve((size_t)N * 128 * 2);
  short* vb = (short*)carve((size_t)N * 128 * 2);
  float* alpha = (float*)carve((size_t)E * 4 * 4);
  unsigned* mmax = (unsigned*)carve((size_t)N * 4 * 4);
  float* denom = (float*)carve((size_t)N * 4 * 4);
  float* outacc = hacc;

  const int B = 256;

  hipMemsetAsync(flag, 0, 4, stream);
  hipMemsetAsync(deg, 0, (size_t)N * 4, stream);
  hipMemsetAsync(hacc, 0, (size_t)N * 128 * 4, stream);
  hipMemsetAsync(denom, 0, (size_t)N * 16, stream);

  detect_dtype<<<1, 256, 0, stream>>>((const unsigned short*)x, flag);
  conv_bias<<<3, B, 0, stream>>>(bg, bq, bk, bv, bs, flag, bgf, bias512);

  deg_kernel<<<(E + B - 1) / B, B, 0, stream>>>(ei, deg, E);
  dinv_kernel<<<(N + B - 1) / B, B, 0, stream>>>(deg, N);

  naive_h0<<<(int)((NC + B - 1) / B), B, 0, stream>>>(x, Wg, flag, h0, N);
  gcn_scatter<<<(int)(((long long)E * 128 + B - 1) / B), B, 0, stream>>>(ei, deg, h0, hacc, E);
  gcn_finish<<<(int)((NC + B - 1) / B), B, 0, stream>>>(hacc, h0, deg, bgf, NC);

  naive_qkvs<<<(int)((NC * 4 + B - 1) / B), B, 0, stream>>>(h0, Wq, Wk, Wv, Ws, flag,
                                                           bias512, qb, kb, vb, outacc, N);

  fill_mmax<<<(N * 4 + B - 1) / B, B, 0, stream>>>(mmax, N * 4);
  attn_alpha<<<(E * 4 + B - 1) / B, B, 0, stream>>>(ei, qb, kb, alpha, mmax, E);
  attn_denom<<<(E * 4 + B - 1) / B, B, 0, stream>>>(ei, mmax, alpha, denom, E);
  rdenom_kernel<<<(N * 4 + B - 1) / B, B, 0, stream>>>(denom, N * 4);
  attn_scatter<<<(int)(((long long)E * 128 + B - 1) / B), B, 0, stream>>>(ei, alpha, denom, vb, outacc, E);
  copy_out<<<(int)((NC + B - 1) / B), B, 0, stream>>>(outacc, out, NC);
}

// Round 7
// 837.603 us; speedup vs baseline: 1.9761x; 1.9761x over previous
//
#include <hip/hip_runtime.h>
#include <hip/hip_bf16.h>

typedef __attribute__((ext_vector_type(8))) short short8;
typedef __attribute__((ext_vector_type(4))) float floatx4;

// flag==1: inputs fp32 (proven R2->R3); flag==0: bf16.
__device__ __forceinline__ float ld_f(const void* p, int f32, int i) {
  if (f32) return ((const float*)p)[i];
  unsigned short u = ((const unsigned short*)p)[i];
  return __uint_as_float(((unsigned)u) << 16);
}
__device__ __forceinline__ short ld_bf(const void* p, int f32, int i) {
  if (!f32) return ((const short*)p)[i];
  __hip_bfloat16 h = __float2bfloat16(((const float*)p)[i]);
  return *reinterpret_cast<short*>(&h);
}
__device__ __forceinline__ float bf_to_f(short s) {
  return __uint_as_float(((unsigned)(unsigned short)s) << 16);
}
__device__ __forceinline__ short f_to_bf(float v) {
  __hip_bfloat16 h = __float2bfloat16(v);
  return *reinterpret_cast<short*>(&h);
}

__global__ void detect_dtype(const unsigned short* __restrict__ xs, int* __restrict__ flag) {
  int t = threadIdx.x;
  int bad = 0;
  for (int j = 2 * t; j < 16384; j += 512) {
    unsigned e = (xs[j] >> 7) & 0xFF;
    if (e >= 0xF0) bad = 1;
  }
  if (bad) atomicOr(flag, 1);
}

__global__ void conv_x(const void* __restrict__ x, const int* __restrict__ flag,
                       short* __restrict__ xbf, long long total) {
  long long i = (long long)blockIdx.x * blockDim.x + threadIdx.x;
  if (i >= total) return;
  xbf[i] = ld_bf(x, *flag, (int)i);
}

__global__ void conv_bias(const void* bg, const void* bq, const void* bk,
                          const void* bv, const void* bs, const int* __restrict__ flag,
                          float* __restrict__ bgf, float* __restrict__ bias512) {
  int tid = blockIdx.x * blockDim.x + threadIdx.x;
  int f = *flag;
  if (tid < 128) bgf[tid] = ld_f(bg, f, tid);
  else if (tid < 640) {
    int t = tid - 128;
    const void* b = (t < 128) ? bq : (t < 256) ? bk : (t < 384) ? bv : bs;
    bias512[t] = ld_f(b, f, t & 127);
  }
}

// ---- weight packing into MFMA B-fragment order (validated on-HW R3-R5) ----
// lane L holds B[k=quad*8+j][n=L&15]; packed idx [(tn*4+kb)*64+lane]*8+j.
__global__ void pack_w128(const void* __restrict__ W, const int* __restrict__ flag,
                          short* __restrict__ Bp) {
  int tid = blockIdx.x * blockDim.x + threadIdx.x;  // 8 tn * 4 kb * 64 lanes
  if (tid >= 8 * 4 * 64) return;
  int f = *flag;
  int lane = tid & 63, kb = (tid >> 6) & 3, tn = tid >> 8;
  int k0 = kb * 32 + (lane >> 4) * 8;
  int n = tn * 16 + (lane & 15);
  short* dst = Bp + (size_t)tid * 8;
#pragma unroll
  for (int j = 0; j < 8; ++j) dst[j] = ld_bf(W, f, (k0 + j) * 128 + n);
}

__global__ void pack_qkvs(const void* Wq, const void* Wk, const void* Wv, const void* Ws,
                          const int* __restrict__ flag, short* __restrict__ Bp) {
  int tid = blockIdx.x * blockDim.x + threadIdx.x;  // 32 tn * 4 kb * 64 lanes
  if (tid >= 32 * 4 * 64) return;
  int f = *flag;
  int lane = tid & 63, kb = (tid >> 6) & 3, tn = tid >> 8;
  int k0 = kb * 32 + (lane >> 4) * 8;
  int n = tn * 16 + (lane & 15);
  const void* W = (n < 128) ? Wq : (n < 256) ? Wk : (n < 384) ? Wv : Ws;
  int col = n & 127;
  short* dst = Bp + (size_t)tid * 8;
#pragma unroll
  for (int j = 0; j < 8; ++j) dst[j] = ld_bf(W, f, (k0 + j) * 128 + col);
}

// ---- MFMA GEMM h0 = x @ W_gcn, fp32 out. One wave: 16 rows x all 128 cols.
__global__ void gemm_h0(const short* __restrict__ A, const short* __restrict__ Bp,
                        float* __restrict__ C, int M) {
  int wv = (blockIdx.x * blockDim.x + threadIdx.x) >> 6;
  int lane = threadIdx.x & 63;
  int tilesM = (M + 15) >> 4;
  if (wv >= tilesM) return;
  int tm = wv;
  int m = tm * 16 + (lane & 15);
  int mc = m < M ? m : M - 1;
  int quad = lane >> 4;
  const short* Arow = A + (size_t)mc * 128 + quad * 8;
  short8 a[4];
#pragma unroll
  for (int kb = 0; kb < 4; ++kb) a[kb] = *(const short8*)(Arow + kb * 32);
  floatx4 acc[8];
#pragma unroll
  for (int tn = 0; tn < 8; ++tn) acc[tn] = (floatx4){0.f, 0.f, 0.f, 0.f};
#pragma unroll
  for (int kb = 0; kb < 4; ++kb) {
#pragma unroll
    for (int tn = 0; tn < 8; ++tn) {
      short8 b8 = *(const short8*)(Bp + ((size_t)(tn * 4 + kb) * 64 + lane) * 8);
      acc[tn] = __builtin_amdgcn_mfma_f32_16x16x32_bf16(a[kb], b8, acc[tn], 0, 0, 0);
    }
  }
  int row0 = tm * 16 + quad * 4;  // C/D map validated on-HW (R4 cmap probe)
  int cl = lane & 15;
#pragma unroll
  for (int tn = 0; tn < 8; ++tn)
#pragma unroll
    for (int r = 0; r < 4; ++r)
      if (row0 + r < M) C[(size_t)(row0 + r) * 128 + tn * 16 + cl] = acc[tn][r];
}

// ---- MFMA GEMM [q|k|v|s] = h @ Wp + bias. Wave: 16 rows x 128-col group.
// tng 0->q(bf16), 1->k(bf16), 2->v(bf16), 3->outacc(fp32, skip term).
__global__ void gemm_qkvs(const short* __restrict__ A, const short* __restrict__ Bp,
                          const float* __restrict__ bias512, short* __restrict__ qb,
                          short* __restrict__ kb_, short* __restrict__ vb,
                          float* __restrict__ outacc, int M) {
  int wv = (blockIdx.x * blockDim.x + threadIdx.x) >> 6;
  int lane = threadIdx.x & 63;
  int tilesM = (M + 15) >> 4;
  if (wv >= tilesM * 4) return;
  int tng = wv & 3, tm = wv >> 2;
  int m = tm * 16 + (lane & 15);
  int mc = m < M ? m : M - 1;
  int quad = lane >> 4;
  const short* Arow = A + (size_t)mc * 128 + quad * 8;
  short8 a[4];
#pragma unroll
  for (int kb = 0; kb < 4; ++kb) a[kb] = *(const short8*)(Arow + kb * 32);
  floatx4 acc[8];
#pragma unroll
  for (int j = 0; j < 8; ++j) acc[j] = (floatx4){0.f, 0.f, 0.f, 0.f};
#pragma unroll
  for (int kb = 0; kb < 4; ++kb) {
#pragma unroll
    for (int j = 0; j < 8; ++j) {
      int tn = tng * 8 + j;
      short8 b8 = *(const short8*)(Bp + ((size_t)(tn * 4 + kb) * 64 + lane) * 8);
      acc[j] = __builtin_amdgcn_mfma_f32_16x16x32_bf16(a[kb], b8, acc[j], 0, 0, 0);
    }
  }
  int row0 = tm * 16 + quad * 4;
  int cl = lane & 15;
  short* outs = (tng == 0) ? qb : (tng == 1) ? kb_ : vb;
#pragma unroll
  for (int j = 0; j < 8; ++j) {
    int cc = j * 16 + cl;          // 0..127 within group
    float b = bias512[tng * 128 + cc];
#pragma unroll
    for (int r = 0; r < 4; ++r) {
      int row = row0 + r;
      if (row >= M) continue;
      float val = acc[j][r] + b;
      if (tng == 3) outacc[(size_t)row * 128 + cc] = val;
      else          outs[(size_t)row * 128 + cc] = f_to_bf(val);
    }
  }
}

// ---------------- GCN ----------------
__global__ void deg_kernel(const int* __restrict__ ei, float* __restrict__ deg, int E) {
  int e = blockIdx.x * blockDim.x + threadIdx.x;
  if (e >= E) return;
  atomicAdd(&deg[ei[E + e]], 1.0f);
}

__global__ void dinv_kernel(float* __restrict__ deg, int N) {
  int i = blockIdx.x * blockDim.x + threadIdx.x;
  if (i >= N) return;
  deg[i] = rsqrtf(deg[i] + 1.0f);
}

__global__ void gcn_scatter(const int* __restrict__ ei, const float* __restrict__ dinv,
                            const float* __restrict__ h0, float* __restrict__ hacc, int E) {
  long long tid = (long long)blockIdx.x * blockDim.x + threadIdx.x;
  int e = (int)(tid >> 7), c = (int)(tid & 127);
  if (e >= E) return;
  int s = ei[e], t = ei[E + e];
  float coef = dinv[s] * dinv[t];
  atomicAdd(hacc + (size_t)t * 128 + c, h0[(size_t)s * 128 + c] * coef);
}

// h <- relu(hacc + h0*dinv^2 + bg), written as bf16 (GEMM A-operand).
__global__ void gcn_finish(const float* __restrict__ hacc, const float* __restrict__ h0,
                           const float* __restrict__ dinv, const float* __restrict__ bgf,
                           short* __restrict__ hbf, long long total) {
  long long i = (long long)blockIdx.x * blockDim.x + threadIdx.x;
  if (i >= total) return;
  int n = (int)(i >> 7), c = (int)(i & 127);
  float di = dinv[n];
  float v = hacc[i] + h0[i] * di * di + bgf[c];
  hbf[i] = f_to_bf(v > 0.f ? v : 0.f);
}

// ---------------- attention ----------------
__global__ void fill_mmax(unsigned* __restrict__ mmax, int total) {
  int i = blockIdx.x * blockDim.x + threadIdx.x;
  if (i < total) mmax[i] = 0x007FFFFFu;  // ordered-uint -inf
}

__global__ void attn_alpha(const int* __restrict__ ei, const short* __restrict__ qb,
                           const short* __restrict__ kb, float* __restrict__ alpha,
                           unsigned* __restrict__ mmax, int E) {
  int tid = blockIdx.x * blockDim.x + threadIdx.x;
  if (tid >= E * 4) return;
  int e = tid >> 2, h = tid & 3;
  int s = ei[e], t = ei[E + e];
  const short8* qp = (const short8*)(qb + (size_t)t * 128 + h * 32);
  const short8* kp = (const short8*)(kb + (size_t)s * 128 + h * 32);
  float dot = 0.f;
#pragma unroll
  for (int b = 0; b < 4; ++b) {
    short8 qa = qp[b], ka = kp[b];
#pragma unroll
    for (int j = 0; j < 8; ++j) dot += bf_to_f(qa[j]) * bf_to_f(ka[j]);
  }
  dot *= 0.17677669529663687f;  // 1/sqrt(32)
  alpha[tid] = dot;
  unsigned bits = __float_as_uint(dot);
  unsigned mapped = (bits & 0x80000000u) ? ~bits : (bits | 0x80000000u);
  atomicMax(&mmax[(size_t)t * 4 + h], mapped);
}

__global__ void attn_denom(const int* __restrict__ ei, const unsigned* __restrict__ mmax,
                           float* __restrict__ alpha, float* __restrict__ denom, int E) {
  int tid = blockIdx.x * blockDim.x + threadIdx.x;
  if (tid >= E * 4) return;
  int e = tid >> 2, h = tid & 3;
  int t = ei[E + e];
  unsigned mm = mmax[(size_t)t * 4 + h];
  float mv = (mm & 0x80000000u) ? __uint_as_float(mm ^ 0x80000000u) : __uint_as_float(~mm);
  float ea = __expf(alpha[tid] - mv);
  alpha[tid] = ea;
  atomicAdd(&denom[(size_t)t * 4 + h], ea);
}

__global__ void rdenom_kernel(float* __restrict__ denom, int total) {
  int i = blockIdx.x * blockDim.x + threadIdx.x;
  if (i >= total) return;
  float d = denom[i];
  denom[i] = d > 0.f ? 1.f / d : 0.f;
}

__global__ void attn_scatter(const int* __restrict__ ei, const float* __restrict__ ea,
                             const float* __restrict__ rdenom, const short* __restrict__ vb,
                             float* __restrict__ outacc, int E) {
  long long tid = (long long)blockIdx.x * blockDim.x + threadIdx.x;
  int e = (int)(tid >> 7), c = (int)(tid & 127);
  if (e >= E) return;
  int s = ei[e], t = ei[E + e];
  int h = c >> 5;
  float w = ea[(size_t)e * 4 + h] * rdenom[(size_t)t * 4 + h];
  float val = w * bf_to_f(vb[(size_t)s * 128 + c]);
  atomicAdd(outacc + (size_t)t * 128 + c, val);
}

__global__ void copy_out(const float* __restrict__ acc, float* __restrict__ out,
                         long long total) {
  long long i = (long long)blockIdx.x * blockDim.x + threadIdx.x;
  if (i < total) out[i] = acc[i];
}

// ---------------- launch ----------------
extern "C" void kernel_launch(void* const* d_in, const int* in_sizes, int n_in,
                              void* d_out, int out_size, void* d_ws, size_t ws_size,
                              hipStream_t stream) {
  const void* x  = d_in[0];
  const int* ei  = (const int*)d_in[1];
  const void* Wg = d_in[2];
  const void* bg = d_in[3];
  const void* Wq = d_in[4];
  const void* bq = d_in[5];
  const void* Wk = d_in[6];
  const void* bk = d_in[7];
  const void* Wv = d_in[8];
  const void* bv = d_in[9];
  const void* Ws = d_in[10];
  const void* bs = d_in[11];
  float* out = (float*)d_out;

  const int N = in_sizes[0] / 128;
  const int E = in_sizes[1] / 2;
  long long NC = (long long)N * 128;
  int tilesM = (N + 15) / 16;

  // ---- workspace carve (256B aligned) — ~114 MB (< proven 116 MB) ----
  char* ws = (char*)d_ws;
  size_t off = 0;
  auto carve = [&](size_t bytes) -> void* {
    void* p = ws + off;
    off += (bytes + 255) & ~(size_t)255;
    return p;
  };
  int* flag = (int*)carve(256);
  float* bias512 = (float*)carve(512 * 4);
  float* bgf = (float*)carve(128 * 4);
  float* deg = (float*)carve((size_t)N * 4);
  short* WpG = (short*)carve((size_t)16384 * 2);
  short* WpQ = (short*)carve((size_t)65536 * 2);
  float* h0 = (float*)carve((size_t)N * 128 * 4);    // fp32, GCN scatter source
  float* hacc = (float*)carve((size_t)N * 128 * 4);  // -> outacc
  short* xbf = (short*)carve((size_t)N * 128 * 2);   // x bf16; dead after gemm_h0 -> hbf
  short* hbf = xbf;
  short* qb = (short*)carve((size_t)N * 128 * 2);
  short* kb = (short*)carve((size_t)N * 128 * 2);
  short* vb = (short*)carve((size_t)N * 128 * 2);
  float* alpha = (float*)carve((size_t)E * 4 * 4);
  unsigned* mmax = (unsigned*)carve((size_t)N * 4 * 4);
  float* denom = (float*)carve((size_t)N * 4 * 4);
  float* outacc = hacc;

  const int B = 256;

  hipMemsetAsync(flag, 0, 4, stream);
  hipMemsetAsync(deg, 0, (size_t)N * 4, stream);
  hipMemsetAsync(hacc, 0, (size_t)N * 128 * 4, stream);
  hipMemsetAsync(denom, 0, (size_t)N * 16, stream);

  detect_dtype<<<1, 256, 0, stream>>>((const unsigned short*)x, flag);
  conv_bias<<<3, B, 0, stream>>>(bg, bq, bk, bv, bs, flag, bgf, bias512);
  conv_x<<<(int)((NC + B - 1) / B), B, 0, stream>>>(x, flag, xbf, NC);
  pack_w128<<<8, B, 0, stream>>>(Wg, flag, WpG);
  pack_qkvs<<<32, B, 0, stream>>>(Wq, Wk, Wv, Ws, flag, WpQ);

  deg_kernel<<<(E + B - 1) / B, B, 0, stream>>>(ei, deg, E);
  dinv_kernel<<<(N + B - 1) / B, B, 0, stream>>>(deg, N);

  gemm_h0<<<(tilesM + 3) / 4, B, 0, stream>>>(xbf, WpG, h0, N);
  gcn_scatter<<<(int)(((long long)E * 128 + B - 1) / B), B, 0, stream>>>(ei, deg, h0, hacc, E);
  gcn_finish<<<(int)((NC + B - 1) / B), B, 0, stream>>>(hacc, h0, deg, bgf, hbf, NC);

  // hacc consumed -> outacc (tng==3 epilogue fully overwrites it).
  gemm_qkvs<<<(tilesM * 4 + 3) / 4, B, 0, stream>>>(hbf, WpQ, bias512, qb, kb, vb, outacc, N);

  fill_mmax<<<(N * 4 + B - 1) / B, B, 0, stream>>>(mmax, N * 4);
  attn_alpha<<<(E * 4 + B - 1) / B, B, 0, stream>>>(ei, qb, kb, alpha, mmax, E);
  attn_denom<<<(E * 4 + B - 1) / B, B, 0, stream>>>(ei, mmax, alpha, denom, E);
  rdenom_kernel<<<(N * 4 + B - 1) / B, B, 0, stream>>>(denom, N * 4);
  attn_scatter<<<(int)(((long long)E * 128 + B - 1) / B), B, 0, stream>>>(ei, alpha, denom, vb, outacc, E);
  copy_out<<<(int)((NC + B - 1) / B), B, 0, stream>>>(outacc, out, NC);
}

// Round 8
// 537.630 us; speedup vs baseline: 3.0786x; 1.5580x over previous
//
#include <hip/hip_runtime.h>
#include <hip/hip_bf16.h>

typedef __attribute__((ext_vector_type(8))) short short8;
typedef __attribute__((ext_vector_type(4))) float floatx4;

// flag==1: inputs fp32 (proven R2->R3); flag==0: bf16.
__device__ __forceinline__ float ld_f(const void* p, int f32, int i) {
  if (f32) return ((const float*)p)[i];
  unsigned short u = ((const unsigned short*)p)[i];
  return __uint_as_float(((unsigned)u) << 16);
}
__device__ __forceinline__ short ld_bf(const void* p, int f32, int i) {
  if (!f32) return ((const short*)p)[i];
  __hip_bfloat16 h = __float2bfloat16(((const float*)p)[i]);
  return *reinterpret_cast<short*>(&h);
}
__device__ __forceinline__ unsigned short f_to_bfu(float v) {
  __hip_bfloat16 h = __float2bfloat16(v);
  return *reinterpret_cast<unsigned short*>(&h);
}

__global__ void detect_dtype(const unsigned short* __restrict__ xs, int* __restrict__ flag) {
  int t = threadIdx.x;
  int bad = 0;
  for (int j = 2 * t; j < 16384; j += 512) {
    unsigned e = (xs[j] >> 7) & 0xFF;
    if (e >= 0xF0) bad = 1;
  }
  if (bad) atomicOr(flag, 1);
}

__global__ void conv_x(const void* __restrict__ x, const int* __restrict__ flag,
                       short* __restrict__ xbf, long long total) {
  long long i = (long long)blockIdx.x * blockDim.x + threadIdx.x;
  if (i >= total) return;
  xbf[i] = ld_bf(x, *flag, (int)i);
}

__global__ void conv_bias(const void* bg, const void* bq, const void* bk,
                          const void* bv, const void* bs, const int* __restrict__ flag,
                          float* __restrict__ bgf, float* __restrict__ bias512) {
  int tid = blockIdx.x * blockDim.x + threadIdx.x;
  int f = *flag;
  if (tid < 128) bgf[tid] = ld_f(bg, f, tid);
  else if (tid < 640) {
    int t = tid - 128;
    const void* b = (t < 128) ? bq : (t < 256) ? bk : (t < 384) ? bv : bs;
    bias512[t] = ld_f(b, f, t & 127);
  }
}

// ---- weight packing into MFMA B-fragment order (HW-validated R3-R7) ----
__global__ void pack_w128(const void* __restrict__ W, const int* __restrict__ flag,
                          short* __restrict__ Bp) {
  int tid = blockIdx.x * blockDim.x + threadIdx.x;
  if (tid >= 8 * 4 * 64) return;
  int f = *flag;
  int lane = tid & 63, kb = (tid >> 6) & 3, tn = tid >> 8;
  int k0 = kb * 32 + (lane >> 4) * 8;
  int n = tn * 16 + (lane & 15);
  short* dst = Bp + (size_t)tid * 8;
#pragma unroll
  for (int j = 0; j < 8; ++j) dst[j] = ld_bf(W, f, (k0 + j) * 128 + n);
}

__global__ void pack_qkvs(const void* Wq, const void* Wk, const void* Wv, const void* Ws,
                          const int* __restrict__ flag, short* __restrict__ Bp) {
  int tid = blockIdx.x * blockDim.x + threadIdx.x;
  if (tid >= 32 * 4 * 64) return;
  int f = *flag;
  int lane = tid & 63, kb = (tid >> 6) & 3, tn = tid >> 8;
  int k0 = kb * 32 + (lane >> 4) * 8;
  int n = tn * 16 + (lane & 15);
  const void* W = (n < 128) ? Wq : (n < 256) ? Wk : (n < 384) ? Wv : Ws;
  int col = n & 127;
  short* dst = Bp + (size_t)tid * 8;
#pragma unroll
  for (int j = 0; j < 8; ++j) dst[j] = ld_bf(W, f, (k0 + j) * 128 + col);
}

// ---- MFMA GEMM h0 = x @ W_gcn (fp32 out) ----
__global__ void gemm_h0(const short* __restrict__ A, const short* __restrict__ Bp,
                        float* __restrict__ C, int M) {
  int wv = (blockIdx.x * blockDim.x + threadIdx.x) >> 6;
  int lane = threadIdx.x & 63;
  int tilesM = (M + 15) >> 4;
  if (wv >= tilesM) return;
  int tm = wv;
  int m = tm * 16 + (lane & 15);
  int mc = m < M ? m : M - 1;
  int quad = lane >> 4;
  const short* Arow = A + (size_t)mc * 128 + quad * 8;
  short8 a[4];
#pragma unroll
  for (int kb = 0; kb < 4; ++kb) a[kb] = *(const short8*)(Arow + kb * 32);
  floatx4 acc[8];
#pragma unroll
  for (int tn = 0; tn < 8; ++tn) acc[tn] = (floatx4){0.f, 0.f, 0.f, 0.f};
#pragma unroll
  for (int kb = 0; kb < 4; ++kb) {
#pragma unroll
    for (int tn = 0; tn < 8; ++tn) {
      short8 b8 = *(const short8*)(Bp + ((size_t)(tn * 4 + kb) * 64 + lane) * 8);
      acc[tn] = __builtin_amdgcn_mfma_f32_16x16x32_bf16(a[kb], b8, acc[tn], 0, 0, 0);
    }
  }
  int row0 = tm * 16 + quad * 4;
  int cl = lane & 15;
#pragma unroll
  for (int tn = 0; tn < 8; ++tn)
#pragma unroll
    for (int r = 0; r < 4; ++r)
      if (row0 + r < M) C[(size_t)(row0 + r) * 128 + tn * 16 + cl] = acc[tn][r];
}

// ---- MFMA GEMM [q|k|v|s] = h @ Wp + bias. tng 0->q,1->k,2->v (bf16), 3->skip fp32.
__global__ void gemm_qkvs(const short* __restrict__ A, const short* __restrict__ Bp,
                          const float* __restrict__ bias512, short* __restrict__ qb,
                          short* __restrict__ kb_, short* __restrict__ vb,
                          float* __restrict__ skip, int M) {
  int wv = (blockIdx.x * blockDim.x + threadIdx.x) >> 6;
  int lane = threadIdx.x & 63;
  int tilesM = (M + 15) >> 4;
  if (wv >= tilesM * 4) return;
  int tng = wv & 3, tm = wv >> 2;
  int m = tm * 16 + (lane & 15);
  int mc = m < M ? m : M - 1;
  int quad = lane >> 4;
  const short* Arow = A + (size_t)mc * 128 + quad * 8;
  short8 a[4];
#pragma unroll
  for (int kb = 0; kb < 4; ++kb) a[kb] = *(const short8*)(Arow + kb * 32);
  floatx4 acc[8];
#pragma unroll
  for (int j = 0; j < 8; ++j) acc[j] = (floatx4){0.f, 0.f, 0.f, 0.f};
#pragma unroll
  for (int kb = 0; kb < 4; ++kb) {
#pragma unroll
    for (int j = 0; j < 8; ++j) {
      int tn = tng * 8 + j;
      short8 b8 = *(const short8*)(Bp + ((size_t)(tn * 4 + kb) * 64 + lane) * 8);
      acc[j] = __builtin_amdgcn_mfma_f32_16x16x32_bf16(a[kb], b8, acc[j], 0, 0, 0);
    }
  }
  int row0 = tm * 16 + quad * 4;
  int cl = lane & 15;
  short* outs = (tng == 0) ? qb : (tng == 1) ? kb_ : vb;
#pragma unroll
  for (int j = 0; j < 8; ++j) {
    int cc = j * 16 + cl;
    float b = bias512[tng * 128 + cc];
#pragma unroll
    for (int r = 0; r < 4; ++r) {
      int row = row0 + r;
      if (row >= M) continue;
      float val = acc[j][r] + b;
      if (tng == 3) skip[(size_t)row * 128 + cc] = val;
      else          outs[(size_t)row * 128 + cc] = (short)f_to_bfu(val);
    }
  }
}

// ---------------- CSR build ----------------
__global__ void hist_kernel(const int* __restrict__ ei, int* __restrict__ cnt, int E) {
  int e = blockIdx.x * blockDim.x + threadIdx.x;
  if (e >= E) return;
  atomicAdd(&cnt[ei[E + e]], 1);
}

__global__ void dinv_kernel(const int* __restrict__ cnt, float* __restrict__ dinv, int N) {
  int i = blockIdx.x * blockDim.x + threadIdx.x;
  if (i >= N) return;
  dinv[i] = rsqrtf((float)cnt[i] + 1.0f);  // +1 self-loop
}

// single-block scan: rowptr (inclusive shifted) + cursor (exclusive)
__global__ void scan_kernel(const int* __restrict__ cnt, int* __restrict__ rowptr,
                            int* __restrict__ cursor, int N) {
  __shared__ int sh[1024];
  int t = threadIdx.x;
  int running = 0;
  if (t == 0) rowptr[0] = 0;
  for (int base = 0; base < N; base += 1024) {
    int v = (base + t < N) ? cnt[base + t] : 0;
    sh[t] = v;
    __syncthreads();
    for (int offs = 1; offs < 1024; offs <<= 1) {
      int add = (t >= offs) ? sh[t - offs] : 0;
      __syncthreads();
      sh[t] += add;
      __syncthreads();
    }
    int incl = sh[t];
    if (base + t < N) {
      rowptr[base + t + 1] = running + incl;
      cursor[base + t] = running + incl - v;
    }
    running += sh[1023];
    __syncthreads();
  }
}

__global__ void fill_kernel(const int* __restrict__ ei, int* __restrict__ cursor,
                            int* __restrict__ srcs, int E) {
  int e = blockIdx.x * blockDim.x + threadIdx.x;
  if (e >= E) return;
  int t = ei[E + e];
  int pos = atomicAdd(&cursor[t], 1);
  srcs[pos] = ei[e];
}

// ---- GCN aggregation, gather form. One wave per node; lane = 2 channels. ----
// h[t] = relu( dinv[t]*(sum_s h0[s]*dinv[s] + h0[t]*dinv[t]) + bg ), bf16 out.
__global__ void gcn_gather(const int* __restrict__ rowptr, const int* __restrict__ srcs,
                           const float* __restrict__ dinv, const float* __restrict__ h0,
                           const float* __restrict__ bgf, unsigned* __restrict__ hbf, int N) {
  int node = (int)((blockIdx.x * (long long)blockDim.x + threadIdx.x) >> 6);
  if (node >= N) return;
  int lane = threadIdx.x & 63;
  const float2* h2 = (const float2*)h0;
  int beg = rowptr[node], end = rowptr[node + 1];
  float2 acc = {0.f, 0.f};
  for (int i = beg; i < end; ++i) {
    int s = srcs[i];
    float ds = dinv[s];
    float2 hv = h2[(size_t)s * 64 + lane];
    acc.x += hv.x * ds;
    acc.y += hv.y * ds;
  }
  float dt = dinv[node];
  float2 hs = h2[(size_t)node * 64 + lane];
  float2 bb = ((const float2*)bgf)[lane];
  float vx = (acc.x + hs.x * dt) * dt + bb.x;
  float vy = (acc.y + hs.y * dt) * dt + bb.y;
  vx = vx > 0.f ? vx : 0.f;
  vy = vy > 0.f ? vy : 0.f;
  hbf[(size_t)node * 64 + lane] = (unsigned)f_to_bfu(vx) | ((unsigned)f_to_bfu(vy) << 16);
}

// ---- Fused attention, gather form. One wave per node t.
// lane: head hh=lane>>4, 16 lanes/head, each lane = 2 channels of 32.
// Pass1: max of dots; Pass2: recompute dot, exp-sum, acc += ea*v. No atomics.
__global__ void attn_fused(const int* __restrict__ rowptr, const int* __restrict__ srcs,
                           const unsigned* __restrict__ qb, const unsigned* __restrict__ kb,
                           const unsigned* __restrict__ vb, const float* __restrict__ skip,
                           float* __restrict__ out, int N) {
  int node = (int)((blockIdx.x * (long long)blockDim.x + threadIdx.x) >> 6);
  if (node >= N) return;
  int lane = threadIdx.x & 63;
  unsigned qw = qb[(size_t)node * 64 + lane];
  float qx = __uint_as_float(qw << 16);
  float qy = __uint_as_float(qw & 0xFFFF0000u);
  int beg = rowptr[node], end = rowptr[node + 1];
  const float scale = 0.17677669529663687f;  // 1/sqrt(32)

  float m = -3.0e38f;
  for (int i = beg; i < end; ++i) {
    int s = srcs[i];
    unsigned kw = kb[(size_t)s * 64 + lane];
    float p = qx * __uint_as_float(kw << 16) + qy * __uint_as_float(kw & 0xFFFF0000u);
    p += __shfl_xor(p, 1, 16);
    p += __shfl_xor(p, 2, 16);
    p += __shfl_xor(p, 4, 16);
    p += __shfl_xor(p, 8, 16);
    float dot = p * scale;
    m = fmaxf(m, dot);
  }

  float denom = 0.f;
  float ax = 0.f, ay = 0.f;
  for (int i = beg; i < end; ++i) {
    int s = srcs[i];
    unsigned kw = kb[(size_t)s * 64 + lane];
    float p = qx * __uint_as_float(kw << 16) + qy * __uint_as_float(kw & 0xFFFF0000u);
    p += __shfl_xor(p, 1, 16);
    p += __shfl_xor(p, 2, 16);
    p += __shfl_xor(p, 4, 16);
    p += __shfl_xor(p, 8, 16);
    float ea = __expf(p * scale - m);
    denom += ea;
    unsigned vw = vb[(size_t)s * 64 + lane];
    ax += ea * __uint_as_float(vw << 16);
    ay += ea * __uint_as_float(vw & 0xFFFF0000u);
  }
  float r = denom > 0.f ? 1.f / denom : 0.f;
  float2 sk = ((const float2*)skip)[(size_t)node * 64 + lane];
  float2 o;
  o.x = ax * r + sk.x;
  o.y = ay * r + sk.y;
  ((float2*)out)[(size_t)node * 64 + lane] = o;
}

// ---------------- launch ----------------
extern "C" void kernel_launch(void* const* d_in, const int* in_sizes, int n_in,
                              void* d_out, int out_size, void* d_ws, size_t ws_size,
                              hipStream_t stream) {
  const void* x  = d_in[0];
  const int* ei  = (const int*)d_in[1];
  const void* Wg = d_in[2];
  const void* bg = d_in[3];
  const void* Wq = d_in[4];
  const void* bq = d_in[5];
  const void* Wk = d_in[6];
  const void* bk = d_in[7];
  const void* Wv = d_in[8];
  const void* bv = d_in[9];
  const void* Ws = d_in[10];
  const void* bs = d_in[11];
  float* out = (float*)d_out;

  const int N = in_sizes[0] / 128;
  const int E = in_sizes[1] / 2;
  long long NC = (long long)N * 128;
  int tilesM = (N + 15) / 16;

  // ---- workspace carve (256B aligned) — ~93 MB (< proven 115.6 MB) ----
  char* ws = (char*)d_ws;
  size_t off = 0;
  auto carve = [&](size_t bytes) -> void* {
    void* p = ws + off;
    off += (bytes + 255) & ~(size_t)255;
    return p;
  };
  int* flag = (int*)carve(256);
  float* bias512 = (float*)carve(512 * 4);
  float* bgf = (float*)carve(128 * 4);
  float* dinv = (float*)carve((size_t)N * 4);
  int* cnt = (int*)carve((size_t)N * 4);
  int* rowptr = (int*)carve((size_t)(N + 1) * 4);
  int* cursor = (int*)carve((size_t)N * 4);
  int* srcs = (int*)carve((size_t)E * 4);
  short* WpG = (short*)carve((size_t)16384 * 2);
  short* WpQ = (short*)carve((size_t)65536 * 2);
  float* h0 = (float*)carve((size_t)N * 128 * 4);
  short* xbf = (short*)carve((size_t)N * 128 * 2);  // x bf16; dead after gemm_h0 -> hbf
  short* hbf = xbf;
  short* qb = (short*)carve((size_t)N * 128 * 2);
  short* kb = (short*)carve((size_t)N * 128 * 2);
  short* vb = (short*)carve((size_t)N * 128 * 2);
  float* skip = (float*)carve((size_t)N * 128 * 4);

  const int B = 256;

  hipMemsetAsync(flag, 0, 4, stream);
  hipMemsetAsync(cnt, 0, (size_t)N * 4, stream);

  detect_dtype<<<1, 256, 0, stream>>>((const unsigned short*)x, flag);
  conv_bias<<<3, B, 0, stream>>>(bg, bq, bk, bv, bs, flag, bgf, bias512);
  conv_x<<<(int)((NC + B - 1) / B), B, 0, stream>>>(x, flag, xbf, NC);
  pack_w128<<<8, B, 0, stream>>>(Wg, flag, WpG);
  pack_qkvs<<<32, B, 0, stream>>>(Wq, Wk, Wv, Ws, flag, WpQ);

  hist_kernel<<<(E + B - 1) / B, B, 0, stream>>>(ei, cnt, E);
  dinv_kernel<<<(N + B - 1) / B, B, 0, stream>>>(cnt, dinv, N);
  scan_kernel<<<1, 1024, 0, stream>>>(cnt, rowptr, cursor, N);
  fill_kernel<<<(E + B - 1) / B, B, 0, stream>>>(ei, cursor, srcs, E);

  gemm_h0<<<(tilesM + 3) / 4, B, 0, stream>>>(xbf, WpG, h0, N);
  gcn_gather<<<(N + 3) / 4, B, 0, stream>>>(rowptr, srcs, dinv, h0, bgf,
                                            (unsigned*)hbf, N);
  gemm_qkvs<<<(tilesM * 4 + 3) / 4, B, 0, stream>>>(hbf, WpQ, bias512, qb, kb, vb, skip, N);

  attn_fused<<<(N + 3) / 4, B, 0, stream>>>(rowptr, srcs, (const unsigned*)qb,
                                            (const unsigned*)kb, (const unsigned*)vb,
                                            skip, out, N);
}

// Round 9
// 317.317 us; speedup vs baseline: 5.2162x; 1.6943x over previous
//
#include <hip/hip_runtime.h>
#include <hip/hip_bf16.h>

typedef __attribute__((ext_vector_type(8))) short short8;
typedef __attribute__((ext_vector_type(4))) float floatx4;

// flag==1: inputs fp32 (proven R2->R3); flag==0: bf16.
__device__ __forceinline__ float ld_f(const void* p, int f32, int i) {
  if (f32) return ((const float*)p)[i];
  unsigned short u = ((const unsigned short*)p)[i];
  return __uint_as_float(((unsigned)u) << 16);
}
__device__ __forceinline__ short ld_bf(const void* p, int f32, int i) {
  if (!f32) return ((const short*)p)[i];
  __hip_bfloat16 h = __float2bfloat16(((const float*)p)[i]);
  return *reinterpret_cast<short*>(&h);
}
__device__ __forceinline__ unsigned short f_to_bfu(float v) {
  __hip_bfloat16 h = __float2bfloat16(v);
  return *reinterpret_cast<unsigned short*>(&h);
}

__global__ void detect_dtype(const unsigned short* __restrict__ xs, int* __restrict__ flag) {
  int t = threadIdx.x;
  int bad = 0;
  for (int j = 2 * t; j < 16384; j += 512) {
    unsigned e = (xs[j] >> 7) & 0xFF;
    if (e >= 0xF0) bad = 1;
  }
  if (bad) atomicOr(flag, 1);
}

__global__ void conv_bias(const void* bg, const void* bq, const void* bk,
                          const void* bv, const void* bs, const int* __restrict__ flag,
                          float* __restrict__ bgf, float* __restrict__ bias512) {
  int tid = blockIdx.x * blockDim.x + threadIdx.x;
  int f = *flag;
  if (tid < 128) bgf[tid] = ld_f(bg, f, tid);
  else if (tid < 640) {
    int t = tid - 128;
    const void* b = (t < 128) ? bq : (t < 256) ? bk : (t < 384) ? bv : bs;
    bias512[t] = ld_f(b, f, t & 127);
  }
}

// ---- weight packing into MFMA B-fragment order (HW-validated R3-R8) ----
__global__ void pack_w128(const void* __restrict__ W, const int* __restrict__ flag,
                          short* __restrict__ Bp) {
  int tid = blockIdx.x * blockDim.x + threadIdx.x;
  if (tid >= 8 * 4 * 64) return;
  int f = *flag;
  int lane = tid & 63, kb = (tid >> 6) & 3, tn = tid >> 8;
  int k0 = kb * 32 + (lane >> 4) * 8;
  int n = tn * 16 + (lane & 15);
  short* dst = Bp + (size_t)tid * 8;
#pragma unroll
  for (int j = 0; j < 8; ++j) dst[j] = ld_bf(W, f, (k0 + j) * 128 + n);
}

__global__ void pack_qkvs(const void* Wq, const void* Wk, const void* Wv, const void* Ws,
                          const int* __restrict__ flag, short* __restrict__ Bp) {
  int tid = blockIdx.x * blockDim.x + threadIdx.x;
  if (tid >= 32 * 4 * 64) return;
  int f = *flag;
  int lane = tid & 63, kb = (tid >> 6) & 3, tn = tid >> 8;
  int k0 = kb * 32 + (lane >> 4) * 8;
  int n = tn * 16 + (lane & 15);
  const void* W = (n < 128) ? Wq : (n < 256) ? Wk : (n < 384) ? Wv : Ws;
  int col = n & 127;
  short* dst = Bp + (size_t)tid * 8;
#pragma unroll
  for (int j = 0; j < 8; ++j) dst[j] = ld_bf(W, f, (k0 + j) * 128 + col);
}

// ---- MFMA GEMM h0 = x @ W_gcn, bf16 out; reads x (fp32 or bf16) directly ----
__global__ void gemm_h0(const void* __restrict__ X, const int* __restrict__ flag,
                        const short* __restrict__ Bp, short* __restrict__ C, int M) {
  int wv = (blockIdx.x * blockDim.x + threadIdx.x) >> 6;
  int lane = threadIdx.x & 63;
  int tilesM = (M + 15) >> 4;
  if (wv >= tilesM) return;
  int f = *flag;
  int tm = wv;
  int m = tm * 16 + (lane & 15);
  int mc = m < M ? m : M - 1;
  int quad = lane >> 4;
  short8 a[4];
  if (f) {
    const float* xr = (const float*)X + (size_t)mc * 128 + quad * 8;
#pragma unroll
    for (int kb = 0; kb < 4; ++kb)
#pragma unroll
      for (int j = 0; j < 8; ++j) a[kb][j] = (short)f_to_bfu(xr[kb * 32 + j]);
  } else {
    const short* xr = (const short*)X + (size_t)mc * 128 + quad * 8;
#pragma unroll
    for (int kb = 0; kb < 4; ++kb) a[kb] = *(const short8*)(xr + kb * 32);
  }
  floatx4 acc[8];
#pragma unroll
  for (int tn = 0; tn < 8; ++tn) acc[tn] = (floatx4){0.f, 0.f, 0.f, 0.f};
#pragma unroll
  for (int kb = 0; kb < 4; ++kb) {
#pragma unroll
    for (int tn = 0; tn < 8; ++tn) {
      short8 b8 = *(const short8*)(Bp + ((size_t)(tn * 4 + kb) * 64 + lane) * 8);
      acc[tn] = __builtin_amdgcn_mfma_f32_16x16x32_bf16(a[kb], b8, acc[tn], 0, 0, 0);
    }
  }
  int row0 = tm * 16 + quad * 4;
  int cl = lane & 15;
#pragma unroll
  for (int tn = 0; tn < 8; ++tn)
#pragma unroll
    for (int r = 0; r < 4; ++r)
      if (row0 + r < M) C[(size_t)(row0 + r) * 128 + tn * 16 + cl] = (short)f_to_bfu(acc[tn][r]);
}

// ---- MFMA GEMM [q|k|v|s] = h @ Wp + bias. tng 0->q,1->k,2->v (bf16), 3->skip fp32.
__global__ void gemm_qkvs(const short* __restrict__ A, const short* __restrict__ Bp,
                          const float* __restrict__ bias512, short* __restrict__ qb,
                          short* __restrict__ kb_, short* __restrict__ vb,
                          float* __restrict__ skip, int M) {
  int wv = (blockIdx.x * blockDim.x + threadIdx.x) >> 6;
  int lane = threadIdx.x & 63;
  int tilesM = (M + 15) >> 4;
  if (wv >= tilesM * 4) return;
  int tng = wv & 3, tm = wv >> 2;
  int m = tm * 16 + (lane & 15);
  int mc = m < M ? m : M - 1;
  int quad = lane >> 4;
  const short* Arow = A + (size_t)mc * 128 + quad * 8;
  short8 a[4];
#pragma unroll
  for (int kb = 0; kb < 4; ++kb) a[kb] = *(const short8*)(Arow + kb * 32);
  floatx4 acc[8];
#pragma unroll
  for (int j = 0; j < 8; ++j) acc[j] = (floatx4){0.f, 0.f, 0.f, 0.f};
#pragma unroll
  for (int kb = 0; kb < 4; ++kb) {
#pragma unroll
    for (int j = 0; j < 8; ++j) {
      int tn = tng * 8 + j;
      short8 b8 = *(const short8*)(Bp + ((size_t)(tn * 4 + kb) * 64 + lane) * 8);
      acc[j] = __builtin_amdgcn_mfma_f32_16x16x32_bf16(a[kb], b8, acc[j], 0, 0, 0);
    }
  }
  int row0 = tm * 16 + quad * 4;
  int cl = lane & 15;
  short* outs = (tng == 0) ? qb : (tng == 1) ? kb_ : vb;
#pragma unroll
  for (int j = 0; j < 8; ++j) {
    int cc = j * 16 + cl;
    float b = bias512[tng * 128 + cc];
#pragma unroll
    for (int r = 0; r < 4; ++r) {
      int row = row0 + r;
      if (row >= M) continue;
      float val = acc[j][r] + b;
      if (tng == 3) skip[(size_t)row * 128 + cc] = val;
      else          outs[(size_t)row * 128 + cc] = (short)f_to_bfu(val);
    }
  }
}

// ---------------- CSR build ----------------
__global__ void hist_kernel(const int* __restrict__ ei, int* __restrict__ cnt, int E) {
  int e = blockIdx.x * blockDim.x + threadIdx.x;
  if (e >= E) return;
  atomicAdd(&cnt[ei[E + e]], 1);
}

__global__ void dinv_kernel(const int* __restrict__ cnt, float* __restrict__ dinv, int N) {
  int i = blockIdx.x * blockDim.x + threadIdx.x;
  if (i >= N) return;
  dinv[i] = rsqrtf((float)cnt[i] + 1.0f);  // +1 self-loop
}

// 3-phase multiblock scan
__global__ void scanA(const int* __restrict__ cnt, int* __restrict__ chunkscan,
                      int* __restrict__ partials, int N) {
  __shared__ int sh[1024];
  int t = threadIdx.x;
  int g = blockIdx.x * 1024 + t;
  int v = (g < N) ? cnt[g] : 0;
  sh[t] = v;
  __syncthreads();
  for (int o = 1; o < 1024; o <<= 1) {
    int add = (t >= o) ? sh[t - o] : 0;
    __syncthreads();
    sh[t] += add;
    __syncthreads();
  }
  if (g < N) chunkscan[g] = sh[t];
  if (t == 1023) partials[blockIdx.x] = sh[1023];
}

__global__ void scanB(int* __restrict__ partials, int nb) {
  if (threadIdx.x == 0) {
    int run = 0;
    for (int b = 0; b < nb; ++b) {
      int t = partials[b];
      partials[b] = run;
      run += t;
    }
  }
}

__global__ void scanC(const int* __restrict__ cnt, const int* __restrict__ chunkscan,
                      const int* __restrict__ partials, int* __restrict__ rowptr,
                      int* __restrict__ cursor, int N) {
  int g = blockIdx.x * blockDim.x + threadIdx.x;
  if (g == 0) rowptr[0] = 0;
  if (g >= N) return;
  int inc = chunkscan[g] + partials[g >> 10];
  rowptr[g + 1] = inc;
  cursor[g] = inc - cnt[g];
}

__global__ void fill_kernel(const int* __restrict__ ei, int* __restrict__ cursor,
                            int* __restrict__ srcs, int E) {
  int e = blockIdx.x * blockDim.x + threadIdx.x;
  if (e >= E) return;
  int t = ei[E + e];
  int pos = atomicAdd(&cursor[t], 1);
  srcs[pos] = ei[e];
}

// ---- GCN aggregation, gather form, bf16 h0, 4-edge unroll ----
__global__ void gcn_gather(const int* __restrict__ rowptr, const int* __restrict__ srcs,
                           const float* __restrict__ dinv, const unsigned* __restrict__ h0,
                           const float* __restrict__ bgf, unsigned* __restrict__ hbf, int N) {
  int node = (int)((blockIdx.x * (long long)blockDim.x + threadIdx.x) >> 6);
  if (node >= N) return;
  int lane = threadIdx.x & 63;
  int beg = rowptr[node], end = rowptr[node + 1];
  float ax = 0.f, ay = 0.f;
  int i = beg;
  for (; i + 3 < end; i += 4) {
    int s0 = srcs[i], s1 = srcs[i + 1], s2 = srcs[i + 2], s3 = srcs[i + 3];
    float d0 = dinv[s0], d1 = dinv[s1], d2 = dinv[s2], d3 = dinv[s3];
    unsigned w0 = h0[(size_t)s0 * 64 + lane];
    unsigned w1 = h0[(size_t)s1 * 64 + lane];
    unsigned w2 = h0[(size_t)s2 * 64 + lane];
    unsigned w3 = h0[(size_t)s3 * 64 + lane];
    ax += __uint_as_float(w0 << 16) * d0 + __uint_as_float(w1 << 16) * d1 +
          __uint_as_float(w2 << 16) * d2 + __uint_as_float(w3 << 16) * d3;
    ay += __uint_as_float(w0 & 0xFFFF0000u) * d0 + __uint_as_float(w1 & 0xFFFF0000u) * d1 +
          __uint_as_float(w2 & 0xFFFF0000u) * d2 + __uint_as_float(w3 & 0xFFFF0000u) * d3;
  }
  for (; i < end; ++i) {
    int s = srcs[i];
    float ds = dinv[s];
    unsigned w = h0[(size_t)s * 64 + lane];
    ax += __uint_as_float(w << 16) * ds;
    ay += __uint_as_float(w & 0xFFFF0000u) * ds;
  }
  float dt = dinv[node];
  unsigned hw = h0[(size_t)node * 64 + lane];
  float2 bb = ((const float2*)bgf)[lane];
  float vx = (ax + __uint_as_float(hw << 16) * dt) * dt + bb.x;
  float vy = (ay + __uint_as_float(hw & 0xFFFF0000u) * dt) * dt + bb.y;
  vx = vx > 0.f ? vx : 0.f;
  vy = vy > 0.f ? vy : 0.f;
  hbf[(size_t)node * 64 + lane] = (unsigned)f_to_bfu(vx) | ((unsigned)f_to_bfu(vy) << 16);
}

// ---- Fused attention: single-pass online softmax, 4-edge unroll ----
__device__ __forceinline__ float dotred(float qx, float qy, unsigned kw) {
  float p = qx * __uint_as_float(kw << 16) + qy * __uint_as_float(kw & 0xFFFF0000u);
  p += __shfl_xor(p, 1, 16);
  p += __shfl_xor(p, 2, 16);
  p += __shfl_xor(p, 4, 16);
  p += __shfl_xor(p, 8, 16);
  return p * 0.17677669529663687f;  // 1/sqrt(32)
}
__device__ __forceinline__ void online_upd(float d, unsigned vw, float& m, float& denom,
                                           float& ax, float& ay) {
  float mn = fmaxf(m, d);
  float sc = __expf(m - mn);
  float ea = __expf(d - mn);
  denom = denom * sc + ea;
  ax = ax * sc + ea * __uint_as_float(vw << 16);
  ay = ay * sc + ea * __uint_as_float(vw & 0xFFFF0000u);
  m = mn;
}

__global__ void attn_fused(const int* __restrict__ rowptr, const int* __restrict__ srcs,
                           const unsigned* __restrict__ qb, const unsigned* __restrict__ kb,
                           const unsigned* __restrict__ vb, const float* __restrict__ skip,
                           float* __restrict__ out, int N) {
  int node = (int)((blockIdx.x * (long long)blockDim.x + threadIdx.x) >> 6);
  if (node >= N) return;
  int lane = threadIdx.x & 63;
  unsigned qw = qb[(size_t)node * 64 + lane];
  float qx = __uint_as_float(qw << 16);
  float qy = __uint_as_float(qw & 0xFFFF0000u);
  int beg = rowptr[node], end = rowptr[node + 1];

  float m = -3.0e38f, denom = 0.f, ax = 0.f, ay = 0.f;
  int i = beg;
  for (; i + 3 < end; i += 4) {
    int s0 = srcs[i], s1 = srcs[i + 1], s2 = srcs[i + 2], s3 = srcs[i + 3];
    unsigned kw0 = kb[(size_t)s0 * 64 + lane];
    unsigned kw1 = kb[(size_t)s1 * 64 + lane];
    unsigned kw2 = kb[(size_t)s2 * 64 + lane];
    unsigned kw3 = kb[(size_t)s3 * 64 + lane];
    unsigned vw0 = vb[(size_t)s0 * 64 + lane];
    unsigned vw1 = vb[(size_t)s1 * 64 + lane];
    unsigned vw2 = vb[(size_t)s2 * 64 + lane];
    unsigned vw3 = vb[(size_t)s3 * 64 + lane];
    float d0 = dotred(qx, qy, kw0);
    float d1 = dotred(qx, qy, kw1);
    float d2 = dotred(qx, qy, kw2);
    float d3 = dotred(qx, qy, kw3);
    online_upd(d0, vw0, m, denom, ax, ay);
    online_upd(d1, vw1, m, denom, ax, ay);
    online_upd(d2, vw2, m, denom, ax, ay);
    online_upd(d3, vw3, m, denom, ax, ay);
  }
  for (; i < end; ++i) {
    int s = srcs[i];
    unsigned kw = kb[(size_t)s * 64 + lane];
    unsigned vw = vb[(size_t)s * 64 + lane];
    online_upd(dotred(qx, qy, kw), vw, m, denom, ax, ay);
  }
  float r = denom > 0.f ? 1.f / denom : 0.f;
  float2 sk = ((const float2*)skip)[(size_t)node * 64 + lane];
  float2 o;
  o.x = ax * r + sk.x;
  o.y = ay * r + sk.y;
  ((float2*)out)[(size_t)node * 64 + lane] = o;
}

// ---------------- launch ----------------
extern "C" void kernel_launch(void* const* d_in, const int* in_sizes, int n_in,
                              void* d_out, int out_size, void* d_ws, size_t ws_size,
                              hipStream_t stream) {
  const void* x  = d_in[0];
  const int* ei  = (const int*)d_in[1];
  const void* Wg = d_in[2];
  const void* bg = d_in[3];
  const void* Wq = d_in[4];
  const void* bq = d_in[5];
  const void* Wk = d_in[6];
  const void* bk = d_in[7];
  const void* Wv = d_in[8];
  const void* bv = d_in[9];
  const void* Ws = d_in[10];
  const void* bs = d_in[11];
  float* out = (float*)d_out;

  const int N = in_sizes[0] / 128;
  const int E = in_sizes[1] / 2;
  int tilesM = (N + 15) / 16;
  int nscan = (N + 1023) / 1024;

  // ---- workspace carve (256B aligned) — ~93 MB (< proven 115.6 MB) ----
  char* ws = (char*)d_ws;
  size_t off = 0;
  auto carve = [&](size_t bytes) -> void* {
    void* p = ws + off;
    off += (bytes + 255) & ~(size_t)255;
    return p;
  };
  int* flag = (int*)carve(256);
  float* bias512 = (float*)carve(512 * 4);
  float* bgf = (float*)carve(128 * 4);
  float* dinv = (float*)carve((size_t)N * 4);
  int* cnt = (int*)carve((size_t)N * 4);
  int* rowptr = (int*)carve((size_t)(N + 1) * 4);
  int* cursor = (int*)carve((size_t)N * 4);
  int* chunkscan = (int*)carve((size_t)N * 4);
  int* partials = (int*)carve((size_t)(nscan + 1) * 4);
  int* srcs = (int*)carve((size_t)E * 4);
  short* WpG = (short*)carve((size_t)16384 * 2);
  short* WpQ = (short*)carve((size_t)65536 * 2);
  short* h0bf = (short*)carve((size_t)N * 128 * 2);
  short* hbf = (short*)carve((size_t)N * 128 * 2);
  short* qb = (short*)carve((size_t)N * 128 * 2);
  short* kb = (short*)carve((size_t)N * 128 * 2);
  short* vb = (short*)carve((size_t)N * 128 * 2);
  float* skip = (float*)carve((size_t)N * 128 * 4);

  const int B = 256;

  hipMemsetAsync(flag, 0, 4, stream);
  hipMemsetAsync(cnt, 0, (size_t)N * 4, stream);

  detect_dtype<<<1, 256, 0, stream>>>((const unsigned short*)x, flag);
  conv_bias<<<3, B, 0, stream>>>(bg, bq, bk, bv, bs, flag, bgf, bias512);
  pack_w128<<<8, B, 0, stream>>>(Wg, flag, WpG);
  pack_qkvs<<<32, B, 0, stream>>>(Wq, Wk, Wv, Ws, flag, WpQ);

  hist_kernel<<<(E + B - 1) / B, B, 0, stream>>>(ei, cnt, E);
  dinv_kernel<<<(N + B - 1) / B, B, 0, stream>>>(cnt, dinv, N);
  scanA<<<nscan, 1024, 0, stream>>>(cnt, chunkscan, partials, N);
  scanB<<<1, 64, 0, stream>>>(partials, nscan);
  scanC<<<(N + B - 1) / B, B, 0, stream>>>(cnt, chunkscan, partials, rowptr, cursor, N);
  fill_kernel<<<(E + B - 1) / B, B, 0, stream>>>(ei, cursor, srcs, E);

  gemm_h0<<<(tilesM + 3) / 4, B, 0, stream>>>(x, flag, WpG, h0bf, N);
  gcn_gather<<<(N + 3) / 4, B, 0, stream>>>(rowptr, srcs, dinv, (const unsigned*)h0bf, bgf,
                                            (unsigned*)hbf, N);
  gemm_qkvs<<<(tilesM * 4 + 3) / 4, B, 0, stream>>>(hbf, WpQ, bias512, qb, kb, vb, skip, N);

  attn_fused<<<(N + 3) / 4, B, 0, stream>>>(rowptr, srcs, (const unsigned*)qb,
                                            (const unsigned*)kb, (const unsigned*)vb,
                                            skip, out, N);
}